// Round 9
// baseline (94.056 us; speedup 1.0000x reference)
//
#include <hip/hip_runtime.h>
#include <math.h>

#define HXc 3.0f
#define HZc 0.25f

// ws layout (float offsets)
#define OFF_TANR 0        // [256*256] tan(theta) row-major [m][l]
#define OFF_F    65536    // [256*256] F[m][b]
#define OFF_CP   131072   // [256*256] cP[m][b] = coef[b]*P[m][b]
#define OFF_NM   196608   // [256] per-m sum_b base*F
#define OFF_DM   196864   // [256] per-m sum_b base
#define OFF_CN   197120   // [256] per-m sum_b cP*F
#define OFF_CD   197376   // [256] per-m sum_b cP

__device__ __forceinline__ float tan_poly(float x) {
    // |x| <= 0.3: rel err < 2e-8
    float y = x * x;
    float p = fmaf(y, 62.0f / 2835.0f, 17.0f / 315.0f);
    p = fmaf(y, p, 2.0f / 15.0f);
    p = fmaf(y, p, 1.0f / 3.0f);
    return x * fmaf(y, p, 1.0f);
}

// 256 blocks (block = m) x 512 threads (8 waves).
// Phase A via LDS-transposed 64-b tiles: stage coalesced theta reads ->
// tan_poly -> tanB[64][257]; compute lane=b, wave=32-l-chunk, serial l
// (register accumulation, zero cross-lane reductions). cos via rsqrt(1+t^2).
__global__ __launch_bounds__(512) void k_fwd(
        const float* __restrict__ theta,
        const float* __restrict__ coef,
        const float* __restrict__ strengths,
        float* __restrict__ ws) {
    int m = blockIdx.x, tid = threadIdx.x;
    __shared__ float tanB[64][257];      // padded: conflict-free both ways
    __shared__ float tmL[256], sLDS[256];
    __shared__ float Flds[256], cPlds[256];
    __shared__ float4 red[8][64];        // per (l-chunk wave, local b) partials
    __shared__ float prp[4];

    if (tid < 256) {
        float x = theta[m * 256 + tid];              // coalesced
        float tn = tan_poly(x);
        tmL[tid] = tn;
        ws[OFF_TANR + m * 256 + tid] = tn;           // row m for k_grad
        sLDS[tid] = (tid < 255) ? strengths[tid] : 0.0f;
        float cm = rsqrtf(fmaf(tn, tn, 1.0f));       // cos(theta[m][l])
        for (int o = 32; o; o >>= 1) cm *= __shfl_xor(cm, o);
        if ((tid & 63) == 0) prp[tid >> 6] = cm;
    }
    __syncthreads();
    float Cpm = prp[0] * prp[1] * prp[2] * prp[3];   // prod_l cos(theta[m][l])
    float coefm = coef[m];

    int c = tid & 255, rp = tid >> 8;                // staging coords
    int bL = tid & 63, w = tid >> 6;                 // compute coords
    int l0 = w * 32;
    float nA = 0.f, dA = 0.f, cNA = 0.f, cDA = 0.f;  // live on tid<64

    for (int t = 0; t < 4; ++t) {
        int b0 = t * 64;
        // ---- stage tile: rows b0..b0+63, coalesced ----
#pragma unroll
        for (int k = 0; k < 32; ++k) {
            int r = 2 * k + rp;
            tanB[r][c] = tan_poly(theta[(b0 + r) * 256 + c]);
        }
        __syncthreads();
        // ---- compute: lane = local b, serial over 32 l's ----
        float p = 1.f, u = 0.f, v = 0.f, z = 0.f, a_prev = 0.f;
        if (l0 > 0) {
            float tb = tanB[bL][l0 - 1];
            float q = tmL[l0 - 1] * tb;
            float inv = __builtin_amdgcn_rcpf(1.0f + q);
            a_prev = fmaf(-q, inv, inv);
        }
#pragma unroll
        for (int j = 0; j < 32; ++j) {
            int l = l0 + j;
            float tb = tanB[bL][l];                  // stride-257: no conflict
            float tm = tmL[l];                       // wave-uniform broadcast
            float q = tm * tb;
            float w1 = 1.0f + q;
            float inv = __builtin_amdgcn_rcpf(w1);
            float cb = rsqrtf(fmaf(tb, tb, 1.0f));   // cos(theta[b][l])
            p *= cb * w1;
            u = fmaf(tm + tb, inv, u);               // sins/cosd
            float a = fmaf(-q, inv, inv);            // coss/cosd
            v += a;
            float sPrev = (l > 0) ? sLDS[l - 1] : 0.0f;
            z = fmaf(sPrev * a_prev, a, z);
            a_prev = a;
        }
        red[w][bL] = make_float4(p, u, v, z);
        __syncthreads();
        // ---- combine 8 l-chunks per b (tid<64), overlaps next stage ----
        if (tid < 64) {
            int b = b0 + tid;
            float4 r0 = red[0][tid], r1 = red[1][tid];
            float4 r2 = red[2][tid], r3 = red[3][tid];
            float4 r4 = red[4][tid], r5 = red[5][tid];
            float4 r6 = red[6][tid], r7 = red[7][tid];
            float P = Cpm * (((r0.x * r1.x) * (r2.x * r3.x)) *
                             ((r4.x * r5.x) * (r6.x * r7.x)));
            float U = ((r0.y + r1.y) + (r2.y + r3.y)) + ((r4.y + r5.y) + (r6.y + r7.y));
            float V = ((r0.z + r1.z) + (r2.z + r3.z)) + ((r4.z + r5.z) + (r6.z + r7.z));
            float Z = ((r0.w + r1.w) + (r2.w + r3.w)) + ((r4.w + r5.w) + (r6.w + r7.w));
            float F = fmaf(HZc, V, fmaf(HXc, U, -Z));   // JZ=-1 folded
            float cP = coef[b] * P;
            Flds[b] = F;
            cPlds[b] = cP;
            float base = coefm * cP;
            dA += base;
            nA = fmaf(base, F, nA);
            cDA += cP;
            cNA = fmaf(cP, F, cNA);
        }
    }
    __syncthreads();
    if (tid < 256) {
        ws[OFF_F + m * 256 + tid] = Flds[tid];
        ws[OFF_CP + m * 256 + tid] = cPlds[tid];
    }
    if (tid < 64) {
        for (int o = 1; o < 64; o <<= 1) {
            nA += __shfl_xor(nA, o);
            dA += __shfl_xor(dA, o);
            cNA += __shfl_xor(cNA, o);
            cDA += __shfl_xor(cDA, o);
        }
        if (tid == 0) {
            ws[OFF_NM + m] = nA;  ws[OFF_DM + m] = dA;
            ws[OFF_CN + m] = cNA; ws[OFF_CD + m] = cDA;
        }
    }
}

// 256 blocks (block = m) x 512 threads (8 waves). Redundant deterministic
// N/D reduction, then phase B (32 b-iters/wave), final outputs direct.
__global__ __launch_bounds__(512) void k_grad(
        const float* __restrict__ coef,
        const float* __restrict__ strengths,
        const float* __restrict__ ws,
        float* __restrict__ out) {
    int m = blockIdx.x, tid = threadIdx.x;
    const float* __restrict__ tanR = ws + OFF_TANR;
    __shared__ float sLDS[256], Flds[256], cPlds[256];
    __shared__ float gN[8 * 256], gD[8 * 256];
    __shared__ float rn[4], rd[4];

    if (tid < 256) {
        sLDS[tid] = (tid < 255) ? strengths[tid] : 0.0f;
        Flds[tid] = ws[OFF_F + m * 256 + tid];
        cPlds[tid] = ws[OFF_CP + m * 256 + tid];
        float nv = ws[OFF_NM + tid], dv = ws[OFF_DM + tid];
        for (int o = 32; o; o >>= 1) {
            nv += __shfl_xor(nv, o);
            dv += __shfl_xor(dv, o);
        }
        if ((tid & 63) == 0) { rn[tid >> 6] = nv; rd[tid >> 6] = dv; }
    }
    __syncthreads();
    float N = rn[0] + rn[1] + rn[2] + rn[3];
    float D = rd[0] + rd[1] + rd[2] + rd[3];
    float E = N / D;                  // bit-identical in every block
    float invD = 1.0f / D;
    float s2 = 2.0f * invD;

    // ---- Phase B: wave = 32-b chunk, lane = 4 consecutive l's ----
    {
        int w = tid >> 6, lane = tid & 63;
        int l0 = lane * 4;
        float coefm = coef[m];
        float4 tm4 = *(const float4*)&tanR[m * 256 + l0];
        float tm[4] = {tm4.x, tm4.y, tm4.z, tm4.w};
        float tm2[4] = {2.0f * tm4.x, 2.0f * tm4.y, 2.0f * tm4.z, 2.0f * tm4.w};
        float sR[4], sL[4];
#pragma unroll
        for (int j = 0; j < 4; ++j) {
            int l = l0 + j;
            sR[j] = sLDS[l];
            sL[j] = (l > 0) ? sLDS[l - 1] : 0.0f;
        }
        float pN[4] = {0.f, 0.f, 0.f, 0.f};
        float pD[4] = {0.f, 0.f, 0.f, 0.f};

        for (int i = 0; i < 32; ++i) {
            int b = w * 32 + i;
            float4 tb4 = *(const float4*)&tanR[b * 256 + l0];   // coalesced, L2-hot
            float tb[4] = {tb4.x, tb4.y, tb4.z, tb4.w};
            float Fv = Flds[b];
            float base = coefm * cPlds[b];

            float A[4], S[4], G[4];
#pragma unroll
            for (int j = 0; j < 4; ++j) {
                float qq = tm[j] * tb[j];
                float w1 = 1.0f + qq;
                float inv = __builtin_amdgcn_rcpf(w1);
                G[j] = (tm[j] - tb[j]) * inv;
                S[j] = fmaf(tm2[j], inv, -G[j]);   // (tm+tb)*inv
                A[j] = fmaf(-qq, inv, inv);        // (1-qq)*inv
            }
            float aLn = __shfl_up(A[3], 1);
            if (lane == 0) aLn = 0.0f;
            float aRn = __shfl_down(A[0], 1);
            if (lane == 63) aRn = 0.0f;
            float am1[4] = {aLn, A[0], A[1], A[2]};
            float ap1[4] = {A[1], A[2], A[3], aRn};
#pragma unroll
            for (int j = 0; j < 4; ++j) {
                float Gxz = fmaf(HXc, A[j], -HZc * S[j])
                          + fmaf(HZc, A[j], HXc * S[j]) * G[j];
                float K = fmaf(-A[j], G[j], S[j]);          // JZ=-1 folded
                float inc = fmaf(sR[j], ap1[j], sL[j] * am1[j]);
                float term = fmaf(K, inc, Gxz);
                term = fmaf(-Fv, G[j], term);
                pN[j] = fmaf(base, term, pN[j]);
                pD[j] = fmaf(-base, G[j], pD[j]);
            }
        }
        ((float4*)gN)[w * 64 + lane] = make_float4(pN[0], pN[1], pN[2], pN[3]);
        ((float4*)gD)[w * 64 + lane] = make_float4(pD[0], pD[1], pD[2], pD[3]);
    }
    __syncthreads();
    if (tid < 256) {
        float sn = 0.0f, sd = 0.0f;
#pragma unroll
        for (int ww = 0; ww < 8; ++ww) {
            sn += gN[ww * 256 + tid];
            sd += gD[ww * 256 + tid];
        }
        out[m * 256 + tid] = s2 * (sn - E * sd);
    }
    if (tid == 0)
        out[65536 + m] = s2 * (ws[OFF_CN + m] - E * ws[OFF_CD + m]);
    if (m == 0 && tid == 1)
        out[65792] = E * (1.0f / 256.0f);
}

extern "C" void kernel_launch(void* const* d_in, const int* in_sizes, int n_in,
                              void* d_out, int out_size, void* d_ws, size_t ws_size,
                              hipStream_t stream) {
    const float* theta = (const float*)d_in[0];
    const float* coef = (const float*)d_in[1];
    const float* strengths = (const float*)d_in[4];
    float* out = (float*)d_out;
    float* ws = (float*)d_ws;

    k_fwd<<<256, 512, 0, stream>>>(theta, coef, strengths, ws);
    k_grad<<<256, 512, 0, stream>>>(coef, strengths, ws, out);
}

// Round 10
// 89.118 us; speedup vs baseline: 1.0554x; 1.0554x over previous
//
#include <hip/hip_runtime.h>
#include <math.h>

#define HXc 3.0f
#define HZc 0.25f

// ws layout (float offsets)
#define OFF_TANR 0        // [256*256] tan(theta) row-major [m][l]
#define OFF_TANT 65536    // [256*256] transposed [l][m]
#define OFF_CPR  131072   // [256] per-row product of cos(theta)
#define OFF_F    131328   // [256*256] F[m][b]
#define OFF_CP   196864   // [256*256] cP[m][b] = coef[b]*P[m][b]
#define OFF_NM   262400   // [512] per-g sum base*F   (g = m*2 + half)
#define OFF_DM   262912   // [512] per-g sum base
#define OFF_CN   263424   // [512] per-g sum cP*F
#define OFF_CD   263936   // [512] per-g sum cP

__device__ __forceinline__ float tan_poly(float x) {
    // |x| <= 0.3: rel err < 2e-8
    float y = x * x;
    float p = fmaf(y, 62.0f / 2835.0f, 17.0f / 315.0f);
    p = fmaf(y, p, 2.0f / 15.0f);
    p = fmaf(y, p, 1.0f / 3.0f);
    return x * fmaf(y, p, 1.0f);
}

__device__ __forceinline__ float cos_poly(float x) {
    float y = x * x;
    float p = fmaf(y, 1.0f / 40320.0f, -1.0f / 720.0f);
    p = fmaf(y, p, 1.0f / 24.0f);
    p = fmaf(y, p, -0.5f);
    return fmaf(y, p, 1.0f);
}

// block = m, thread = l: tan tables (row + transposed) + per-row cos product.
__global__ __launch_bounds__(256) void k_prep(const float* __restrict__ theta,
                                              float* __restrict__ ws) {
    int m = blockIdx.x, t = threadIdx.x;
    float x = theta[m * 256 + t];
    float tn = tan_poly(x);
    float c = cos_poly(x);
    ws[OFF_TANR + m * 256 + t] = tn;
    ws[OFF_TANT + t * 256 + m] = tn;
    float pr = c;
    for (int o = 32; o; o >>= 1) pr *= __shfl_xor(pr, o);
    __shared__ float pp[4];
    if ((t & 63) == 0) pp[t >> 6] = pr;
    __syncthreads();
    if (t == 0) ws[OFF_CPR + m] = pp[0] * pp[1] * pp[2] * pp[3];
}

// 512 blocks (g = m*2 + half; half owns 128 b's) x 512 threads.
// Phase A only (R5's proven geometry): thread -> (l-quarter q, local col bl),
// serial 64 l's with coalesced tanT loads. Writes F/cP + per-g reductions.
__global__ __launch_bounds__(512) void k_fwd(
        const float* __restrict__ coef,
        const float* __restrict__ strengths,
        float* __restrict__ ws) {
    int g = blockIdx.x;
    int m = g >> 1;
    int boff = (g & 1) * 128;
    int tid = threadIdx.x;
    const float* __restrict__ tanR = ws + OFF_TANR;
    const float* __restrict__ tanT = ws + OFF_TANT;
    const float* __restrict__ Cpr = ws + OFF_CPR;

    __shared__ float sLDS[256];          // strengths, padded (s[255]=0)
    __shared__ float tmL[256];           // tan row m
    __shared__ float4 quart[4][128];     // phase-A partials (pw,u,v,z)
    __shared__ float wr[2][4];

    if (tid < 256) {
        sLDS[tid] = (tid < 255) ? strengths[tid] : 0.0f;
        tmL[tid] = tanR[m * 256 + tid];
    }
    __syncthreads();

    {
        int bl = tid & 127, q = tid >> 7;
        int b = boff + bl;
        int l0 = q * 64;
        float pw = 1.0f, u = 0.0f, v = 0.0f, z = 0.0f, a_prev = 0.0f;
        if (q) {
            int l = l0 - 1;
            float qq = tmL[l] * tanT[l * 256 + b];
            a_prev = (1.0f - qq) * __builtin_amdgcn_rcpf(1.0f + qq);
        }
        for (int l = l0; l < l0 + 64; ++l) {
            float tm = tmL[l];                     // LDS broadcast
            float tb = tanT[l * 256 + b];          // coalesced global (L2)
            float qq = tm * tb;
            float w1 = 1.0f + qq;
            float inv = __builtin_amdgcn_rcpf(w1);
            pw *= w1;
            u = fmaf(tm + tb, inv, u);             // sins/cosd
            float a = fmaf(-qq, inv, inv);         // coss/cosd
            v += a;
            float sPrev = (l > 0) ? sLDS[l - 1] : 0.0f;
            z = fmaf(sPrev * a_prev, a, z);
            a_prev = a;
        }
        quart[q][bl] = make_float4(pw, u, v, z);
    }
    __syncthreads();

    if (tid < 128) {
        int b = boff + tid;
        float4 A = quart[0][tid], B = quart[1][tid];
        float4 C = quart[2][tid], Dq = quart[3][tid];
        float P = Cpr[m] * Cpr[b] * (A.x * B.x * C.x * Dq.x);
        float U = A.y + B.y + C.y + Dq.y;
        float V = A.z + B.z + C.z + Dq.z;
        float Z = A.w + B.w + C.w + Dq.w;
        float F = fmaf(HZc, V, fmaf(HXc, U, -Z));  // JZ=-1 folded
        float cP = coef[b] * P;
        ws[OFF_F + m * 256 + b] = F;
        ws[OFF_CP + m * 256 + b] = cP;
        float base = coef[m] * cP;
        float s1 = base, s2 = base * F, s3 = cP, s4 = cP * F;
        for (int o = 32; o; o >>= 1) {
            s1 += __shfl_xor(s1, o);
            s2 += __shfl_xor(s2, o);
            s3 += __shfl_xor(s3, o);
            s4 += __shfl_xor(s4, o);
        }
        if ((tid & 63) == 0) {
            int w = tid >> 6;
            wr[w][0] = s1; wr[w][1] = s2; wr[w][2] = s3; wr[w][3] = s4;
        }
    }
    __syncthreads();
    if (tid == 0) {
        ws[OFF_DM + g] = wr[0][0] + wr[1][0];
        ws[OFF_NM + g] = wr[0][1] + wr[1][1];
        ws[OFF_CD + g] = wr[0][2] + wr[1][2];
        ws[OFF_CN + g] = wr[0][3] + wr[1][3];
    }
}

// 256 blocks (block = m) x 512 threads (8 waves). Redundant deterministic
// N/D reduce (E known up front) -> single-accumulator phase B -> final out.
__global__ __launch_bounds__(512) void k_grad(
        const float* __restrict__ coef,
        const float* __restrict__ strengths,
        const float* __restrict__ ws,
        float* __restrict__ out) {
    int m = blockIdx.x, tid = threadIdx.x;
    const float* __restrict__ tanR = ws + OFF_TANR;
    __shared__ float sLDS[256], Flds[256], cPlds[256];
    __shared__ float gN[8 * 256];
    __shared__ float rn[4], rd[4];

    if (tid < 256) {
        sLDS[tid] = (tid < 255) ? strengths[tid] : 0.0f;
        Flds[tid] = ws[OFF_F + m * 256 + tid];
        cPlds[tid] = ws[OFF_CP + m * 256 + tid];
        float nv = ws[OFF_NM + tid] + ws[OFF_NM + 256 + tid];
        float dv = ws[OFF_DM + tid] + ws[OFF_DM + 256 + tid];
        for (int o = 32; o; o >>= 1) {
            nv += __shfl_xor(nv, o);
            dv += __shfl_xor(dv, o);
        }
        if ((tid & 63) == 0) { rn[tid >> 6] = nv; rd[tid >> 6] = dv; }
    }
    __syncthreads();
    float N = rn[0] + rn[1] + rn[2] + rn[3];
    float D = rd[0] + rd[1] + rd[2] + rd[3];
    float E = N / D;                  // bit-identical in every block
    float invD = 1.0f / D;
    float s2 = 2.0f * invD;

    // ---- Phase B: wave = 32-b chunk, lane = 4 consecutive l's.
    // Single accumulator: out = s2 * sum_b base*(K*inc + Gxz - (F-E)*G) ----
    {
        int w = tid >> 6, lane = tid & 63;
        int l0 = lane * 4;
        float coefm = coef[m];
        float4 tm4 = *(const float4*)&tanR[m * 256 + l0];
        float tm[4] = {tm4.x, tm4.y, tm4.z, tm4.w};
        float tm2[4] = {2.0f * tm4.x, 2.0f * tm4.y, 2.0f * tm4.z, 2.0f * tm4.w};
        float sR[4], sL[4];
#pragma unroll
        for (int j = 0; j < 4; ++j) {
            int l = l0 + j;
            sR[j] = sLDS[l];
            sL[j] = (l > 0) ? sLDS[l - 1] : 0.0f;
        }
        float pN[4] = {0.f, 0.f, 0.f, 0.f};

        for (int i = 0; i < 32; ++i) {
            int b = w * 32 + i;
            float4 tb4 = *(const float4*)&tanR[b * 256 + l0];   // coalesced, L2-hot
            float tb[4] = {tb4.x, tb4.y, tb4.z, tb4.w};
            float Fp = Flds[b] - E;
            float base = coefm * cPlds[b];

            float A[4], S[4], G[4];
#pragma unroll
            for (int j = 0; j < 4; ++j) {
                float qq = tm[j] * tb[j];
                float w1 = 1.0f + qq;
                float inv = __builtin_amdgcn_rcpf(w1);
                G[j] = (tm[j] - tb[j]) * inv;
                S[j] = fmaf(tm2[j], inv, -G[j]);   // (tm+tb)*inv
                A[j] = fmaf(-qq, inv, inv);        // (1-qq)*inv
            }
            float aLn = __shfl_up(A[3], 1);
            if (lane == 0) aLn = 0.0f;
            float aRn = __shfl_down(A[0], 1);
            if (lane == 63) aRn = 0.0f;
            float am1[4] = {aLn, A[0], A[1], A[2]};
            float ap1[4] = {A[1], A[2], A[3], aRn};
#pragma unroll
            for (int j = 0; j < 4; ++j) {
                float Gxz = fmaf(HXc, A[j], -HZc * S[j])
                          + fmaf(HZc, A[j], HXc * S[j]) * G[j];
                float K = fmaf(-A[j], G[j], S[j]);          // JZ=-1 folded
                float inc = fmaf(sR[j], ap1[j], sL[j] * am1[j]);
                float term = fmaf(K, inc, Gxz);
                term = fmaf(-Fp, G[j], term);
                pN[j] = fmaf(base, term, pN[j]);
            }
        }
        ((float4*)gN)[w * 64 + lane] = make_float4(pN[0], pN[1], pN[2], pN[3]);
    }
    __syncthreads();
    if (tid < 256) {
        float sn = 0.0f;
#pragma unroll
        for (int ww = 0; ww < 8; ++ww) sn += gN[ww * 256 + tid];
        out[m * 256 + tid] = s2 * sn;
    }
    if (tid == 0) {
        float cn = ws[OFF_CN + 2 * m] + ws[OFF_CN + 2 * m + 1];
        float cd = ws[OFF_CD + 2 * m] + ws[OFF_CD + 2 * m + 1];
        out[65536 + m] = s2 * (cn - E * cd);
    }
    if (m == 0 && tid == 1)
        out[65792] = E * (1.0f / 256.0f);
}

extern "C" void kernel_launch(void* const* d_in, const int* in_sizes, int n_in,
                              void* d_out, int out_size, void* d_ws, size_t ws_size,
                              hipStream_t stream) {
    const float* theta = (const float*)d_in[0];
    const float* coef = (const float*)d_in[1];
    const float* strengths = (const float*)d_in[4];
    float* out = (float*)d_out;
    float* ws = (float*)d_ws;

    k_prep<<<256, 256, 0, stream>>>(theta, ws);
    k_fwd<<<512, 512, 0, stream>>>(coef, strengths, ws);
    k_grad<<<256, 512, 0, stream>>>(coef, strengths, ws, out);
}